// Round 17
// baseline (127.854 us; speedup 1.0000x reference)
//
#include <hip/hip_runtime.h>
#include <hip/hip_bf16.h>

typedef __hip_bfloat16 bf16;
typedef __attribute__((ext_vector_type(8))) short short8v;
typedef __attribute__((ext_vector_type(4))) float f32x4;

#define NSLICE 32   // B*S
#define HW     1024 // H*W
#define CDIM   256  // C1 == C2 == C
#define KVT    32   // kv tokens per flash inner tile
#define NKT    (HW / KVT)

// dynamic LDS layout (shorts): K0=0, K1=8192, V0=16384, V1=24576, Ps=32768
#define FLASH_LDS_BYTES ((32768 + 2048) * 2)

// ---------------------------------------------------------------------------
// Kernel 0: W^T prep. W f32 [cin][cout] -> wt bf16 [mat][cout][cin].
// Wq (mat 0) prescaled by 1/16.
// ---------------------------------------------------------------------------
__global__ __launch_bounds__(256)
void wt_prep_kernel(const float* __restrict__ Wq, const float* __restrict__ Wk,
                    const float* __restrict__ Wv, bf16* __restrict__ wt)
{
    const int m = blockIdx.x >> 8;
    const int r = blockIdx.x & 255;
    const int tid = threadIdx.x;
    const float* W = (m == 0) ? Wq : (m == 1) ? Wk : Wv;
    const float sc = (m == 0) ? 0.0625f : 1.0f;
    wt[((size_t)m << 16) + (size_t)tid * 256 + r] = __float2bfloat16(W[r * 256 + tid] * sc);
}

// ---------------------------------------------------------------------------
// Kernel 1a: Q projection — single-barrier full-tile staging.
// Stage all 64 tok x 256 cin (32 KB, chunk ^= row&7), ONE sync, then a
// barrier-free MFMA loop. Same math/rounding as round 9.
// ---------------------------------------------------------------------------
__global__ __launch_bounds__(256)
void proj_q_kernel(const float* __restrict__ img, const bf16* __restrict__ wt,
                   const float* __restrict__ bq, bf16* __restrict__ qo)
{
    const int bid   = blockIdx.x;
    const int s     = (bid & 7) * 4 + ((bid >> 3) & 3);
    const int tt    = (bid >> 5) & 15;
    const int chalf = bid >> 9;
    const int t0    = tt * 64;

    const int tid  = threadIdx.x;
    const int wave = tid >> 6;
    const int lane = tid & 63;
    const int lo16 = lane & 15;
    const int hi4  = lane >> 4;
    const int cw0  = chalf * 128 + wave * 32;

    __shared__ short A[64 * 256];   // 32 KB: [tok][cin], 16B chunk ^= (tok&7)

    const int so = tid >> 6, st = tid & 63;
    const float* imgS = img + (size_t)s * CDIM * HW + t0;

    // ---- stage full tile, no inner barriers ----
    #pragma unroll
    for (int kc = 0; kc < 8; ++kc) {
        float r[8];
        #pragma unroll
        for (int j = 0; j < 8; ++j)
            r[j] = imgS[(size_t)(kc * 32 + so * 8 + j) * HW + st];
        short tw[8];
        #pragma unroll
        for (int j = 0; j < 8; ++j) {
            bf16 hb = __float2bfloat16(r[j]);
            tw[j] = *reinterpret_cast<short*>(&hb);
        }
        const int ch = (kc * 4 + so) ^ (st & 7);
        *reinterpret_cast<short8v*>(&A[st * 256 + ch * 8]) = *reinterpret_cast<short8v*>(tw);
    }
    __syncthreads();

    f32x4 aq[2][4];
    #pragma unroll
    for (int a = 0; a < 2; ++a)
        #pragma unroll
        for (int b = 0; b < 4; ++b) aq[a][b] = (f32x4){0.f, 0.f, 0.f, 0.f};

    // ---- barrier-free MFMA loop ----
    #pragma unroll
    for (int kc = 0; kc < 8; ++kc) {
        short8v xi[4];
        #pragma unroll
        for (int nf = 0; nf < 4; ++nf) {
            const int r  = nf * 16 + lo16;
            const int ch = (kc * 4 + hi4) ^ (lo16 & 7);
            xi[nf] = *reinterpret_cast<const short8v*>(&A[r * 256 + ch * 8]);
        }
        const int koff = kc * 32 + hi4 * 8;
        short8v wqf[2];
        #pragma unroll
        for (int mf = 0; mf < 2; ++mf)
            wqf[mf] = *reinterpret_cast<const short8v*>(
                wt + (size_t)(cw0 + mf * 16 + lo16) * 256 + koff);

        #pragma unroll
        for (int mf = 0; mf < 2; ++mf)
            #pragma unroll
            for (int nf = 0; nf < 4; ++nf)
                aq[mf][nf] = __builtin_amdgcn_mfma_f32_16x16x32_bf16(wqf[mf], xi[nf], aq[mf][nf], 0, 0, 0);
    }

    #pragma unroll
    for (int mf = 0; mf < 2; ++mf) {
        const int cb = cw0 + mf * 16 + 4 * hi4;
        const float4 b4 = *reinterpret_cast<const float4*>(bq + cb);
        const float ba[4] = {b4.x * 0.0625f, b4.y * 0.0625f, b4.z * 0.0625f, b4.w * 0.0625f};
        #pragma unroll
        for (int nf = 0; nf < 4; ++nf) {
            const int tok = t0 + nf * 16 + lo16;
            bf16 tq[4];
            #pragma unroll
            for (int g = 0; g < 4; ++g)
                tq[g] = __float2bfloat16(aq[mf][nf][g] + ba[g]);
            *reinterpret_cast<uint2*>(&qo[((size_t)s * HW + tok) * CDIM + cb]) =
                *reinterpret_cast<uint2*>(tq);
        }
    }
}

// ---------------------------------------------------------------------------
// Kernel 1b: K + V projection — single-barrier full-tile staging (same
// scheme as proj_q; math/rounding identical to round 9).
// ---------------------------------------------------------------------------
__global__ __launch_bounds__(256)
void proj_kv_kernel(const float* __restrict__ dep, const bf16* __restrict__ wt,
                    const float* __restrict__ bk, const float* __restrict__ bv,
                    bf16* __restrict__ ko, bf16* __restrict__ vt)
{
    const int bid   = blockIdx.x;
    const int s     = (bid & 7) * 4 + ((bid >> 3) & 3);
    const int tt    = (bid >> 5) & 15;
    const int chalf = bid >> 9;
    const int t0    = tt * 64;

    const int tid  = threadIdx.x;
    const int wave = tid >> 6;
    const int lane = tid & 63;
    const int lo16 = lane & 15;
    const int hi4  = lane >> 4;
    const int cw0  = chalf * 128 + wave * 32;

    __shared__ short A[64 * 256];   // 32 KB: [tok][cin], 16B chunk ^= (tok&7)

    const int so = tid >> 6, st = tid & 63;
    const float* depS = dep + (size_t)s * CDIM * HW + t0;
    const bf16* wtk = wt + (1 << 16);
    const bf16* wtv = wt + (2 << 16);

    // ---- stage full tile, no inner barriers ----
    #pragma unroll
    for (int kc = 0; kc < 8; ++kc) {
        float r[8];
        #pragma unroll
        for (int j = 0; j < 8; ++j)
            r[j] = depS[(size_t)(kc * 32 + so * 8 + j) * HW + st];
        short tw[8];
        #pragma unroll
        for (int j = 0; j < 8; ++j) {
            bf16 hb = __float2bfloat16(r[j]);
            tw[j] = *reinterpret_cast<short*>(&hb);
        }
        const int ch = (kc * 4 + so) ^ (st & 7);
        *reinterpret_cast<short8v*>(&A[st * 256 + ch * 8]) = *reinterpret_cast<short8v*>(tw);
    }
    __syncthreads();

    f32x4 ak[2][4], av[4][2];
    #pragma unroll
    for (int a = 0; a < 2; ++a)
        #pragma unroll
        for (int b = 0; b < 4; ++b) {
            ak[a][b] = (f32x4){0.f, 0.f, 0.f, 0.f};
            av[b][a] = (f32x4){0.f, 0.f, 0.f, 0.f};
        }

    // ---- barrier-free MFMA loop ----
    #pragma unroll
    for (int kc = 0; kc < 8; ++kc) {
        short8v xd[4];
        #pragma unroll
        for (int nf = 0; nf < 4; ++nf) {
            const int r  = nf * 16 + lo16;
            const int ch = (kc * 4 + hi4) ^ (lo16 & 7);
            xd[nf] = *reinterpret_cast<const short8v*>(&A[r * 256 + ch * 8]);
        }
        const int koff = kc * 32 + hi4 * 8;
        short8v wkf[2], wvf[2];
        #pragma unroll
        for (int mf = 0; mf < 2; ++mf) {
            const size_t wrow = (size_t)(cw0 + mf * 16 + lo16) * 256 + koff;
            wkf[mf] = *reinterpret_cast<const short8v*>(wtk + wrow);
            wvf[mf] = *reinterpret_cast<const short8v*>(wtv + wrow);
        }

        #pragma unroll
        for (int mf = 0; mf < 2; ++mf)
            #pragma unroll
            for (int nf = 0; nf < 4; ++nf)
                ak[mf][nf] = __builtin_amdgcn_mfma_f32_16x16x32_bf16(wkf[mf], xd[nf], ak[mf][nf], 0, 0, 0);
        #pragma unroll
        for (int mf = 0; mf < 4; ++mf)
            #pragma unroll
            for (int nf = 0; nf < 2; ++nf)
                av[mf][nf] = __builtin_amdgcn_mfma_f32_16x16x32_bf16(xd[mf], wvf[nf], av[mf][nf], 0, 0, 0);
    }

    #pragma unroll
    for (int mf = 0; mf < 2; ++mf) {
        const int cb = cw0 + mf * 16 + 4 * hi4;
        const float4 b4 = *reinterpret_cast<const float4*>(bk + cb);
        const float ba[4] = {b4.x, b4.y, b4.z, b4.w};
        #pragma unroll
        for (int nf = 0; nf < 4; ++nf) {
            const int tok = t0 + nf * 16 + lo16;
            bf16 tk[4];
            #pragma unroll
            for (int g = 0; g < 4; ++g)
                tk[g] = __float2bfloat16(ak[mf][nf][g] + ba[g]);
            *reinterpret_cast<uint2*>(&ko[((size_t)s * HW + tok) * CDIM + cb]) =
                *reinterpret_cast<uint2*>(tk);
        }
    }
    #pragma unroll
    for (int nf = 0; nf < 2; ++nf) {
        const int c = cw0 + nf * 16 + lo16;
        const float bvv = bv[c];
        #pragma unroll
        for (int mf = 0; mf < 4; ++mf) {
            const int tb = t0 + mf * 16 + 4 * hi4;
            bf16 tv[4];
            #pragma unroll
            for (int g = 0; g < 4; ++g)
                tv[g] = __float2bfloat16(av[mf][nf][g] + bvv);
            *reinterpret_cast<uint2*>(&vt[((size_t)s * CDIM + c) * HW + tb]) =
                *reinterpret_cast<uint2*>(tv);
        }
    }
}

// ---------------------------------------------------------------------------
// Kernel 2: MFMA flash attention (exact round-16 version: double-buffered
// K/V dynamic LDS, one barrier/tile, KVT=32, no-max softmax, XOR swizzles,
// register prefetch, setprio).
// ---------------------------------------------------------------------------
__global__ __launch_bounds__(256)
void flash_mfma_kernel(const bf16* __restrict__ q, const bf16* __restrict__ k,
                       const bf16* __restrict__ vt, const float* __restrict__ img,
                       float* __restrict__ out)
{
    const int bid = blockIdx.x;
    const int s   = (bid & 7) * 4 + ((bid >> 3) & 3);
    const int t0  = (bid >> 5) * 64;

    const int tid  = threadIdx.x;
    const int wave = tid >> 6;
    const int lane = tid & 63;
    const int lo16 = lane & 15;
    const int hi4  = lane >> 4;

    extern __shared__ short SM[];
    // K buffers at 0 / 8192, V buffers at 16384 / 24576, Ps at 32768

    short8v qf[8];
    {
        const bf16* qp = q + ((size_t)s * HW + t0 + wave * 16 + lo16) * CDIM + hi4 * 8;
        #pragma unroll
        for (int kf = 0; kf < 8; ++kf)
            qf[kf] = *reinterpret_cast<const short8v*>(qp + kf * 32);
    }

    f32x4 Oacc[16];
    #pragma unroll
    for (int cf = 0; cf < 16; ++cf) Oacc[cf] = (f32x4){0.f, 0.f, 0.f, 0.f};
    float lp[4] = {0.f, 0.f, 0.f, 0.f};

    const bf16* kS  = k  + (size_t)s * HW * CDIM;
    const bf16* vtS = vt + (size_t)s * CDIM * HW;

    const int krow = tid >> 3;
    const int kch  = tid & 7;
    const int kxor = krow & 7;
    const int vxor = (tid >> 1) & 3;

    short8v kreg[4], vreg[4];
    #pragma unroll
    for (int u = 0; u < 4; ++u) {
        kreg[u] = *reinterpret_cast<const short8v*>(kS + (size_t)krow * CDIM + (kch + 8 * u) * 8);
        vreg[u] = *reinterpret_cast<const short8v*>(vtS + (size_t)tid * HW + u * 8);
    }

    // prologue: publish tile 0 into buffer 0
    #pragma unroll
    for (int u = 0; u < 4; ++u)
        *reinterpret_cast<short8v*>(&SM[krow * 256 + ((kch ^ kxor) + 8 * u) * 8]) = kreg[u];
    #pragma unroll
    for (int u = 0; u < 4; ++u)
        *reinterpret_cast<short8v*>(&SM[16384 + tid * 32 + (u ^ vxor) * 8]) = vreg[u];
    __syncthreads();

    const int pvRow = lo16 * 32 + (hi4 ^ ((lo16 >> 1) & 3)) * 8;
    for (int kt = 0; kt < NKT; ++kt) {
        const int cur = kt & 1;
        const int nxt = cur ^ 1;
        short* Kc = SM + cur * 8192;
        short* Vc = SM + 16384 + cur * 8192;

        if (kt + 1 < NKT) {
            const bf16* src = kS + (size_t)(kt + 1) * KVT * CDIM;
            #pragma unroll
            for (int u = 0; u < 4; ++u) {
                kreg[u] = *reinterpret_cast<const short8v*>(src + (size_t)krow * CDIM + (kch + 8 * u) * 8);
                vreg[u] = *reinterpret_cast<const short8v*>(vtS + (size_t)tid * HW + (kt + 1) * KVT + u * 8);
            }
        }

        // ---- QK^T on current buffer ----
        f32x4 sa[2];
        sa[0] = (f32x4){0.f, 0.f, 0.f, 0.f};
        sa[1] = (f32x4){0.f, 0.f, 0.f, 0.f};
        __builtin_amdgcn_s_setprio(1);
        #pragma unroll
        for (int ks = 0; ks < 8; ++ks) {
            #pragma unroll
            for (int cf = 0; cf < 2; ++cf) {
                const int row = cf * 16 + lo16;
                short8v bfr = *reinterpret_cast<const short8v*>(
                    &Kc[row * 256 + ((4 * ks + hi4) ^ (lo16 & 7)) * 8]);
                sa[cf] = __builtin_amdgcn_mfma_f32_16x16x32_bf16(qf[ks], bfr, sa[cf], 0, 0, 0);
            }
        }
        __builtin_amdgcn_s_setprio(0);

        // ---- P = exp(S); lane-local l partials; P -> LDS swizzled ----
        #pragma unroll
        for (int cf = 0; cf < 2; ++cf)
            #pragma unroll
            for (int g = 0; g < 4; ++g) {
                const float e = __expf(sa[cf][g]);
                lp[g] += e;
                bf16 hb = __float2bfloat16(e);
                const int r = 4 * hi4 + g;
                const int ch = (2 * cf + (lo16 >> 3)) ^ ((r >> 1) & 3);
                SM[32768 + wave * 512 + r * 32 + ch * 8 + (lo16 & 7)] = *reinterpret_cast<short*>(&hb);
            }

        const short8v pa = *reinterpret_cast<const short8v*>(&SM[32768 + wave * 512 + pvRow]);

        // ---- PV on current buffer ----
        __builtin_amdgcn_s_setprio(1);
        #pragma unroll
        for (int cf = 0; cf < 16; ++cf) {
            const int row = cf * 16 + lo16;
            const short8v vb = *reinterpret_cast<const short8v*>(
                &Vc[row * 32 + (hi4 ^ ((lo16 >> 1) & 3)) * 8]);
            Oacc[cf] = __builtin_amdgcn_mfma_f32_16x16x32_bf16(pa, vb, Oacc[cf], 0, 0, 0);
        }
        __builtin_amdgcn_s_setprio(0);

        // ---- publish tile kt+1 into the idle buffer ----
        if (kt + 1 < NKT) {
            short* Kn = SM + nxt * 8192;
            short* Vn = SM + 16384 + nxt * 8192;
            #pragma unroll
            for (int u = 0; u < 4; ++u)
                *reinterpret_cast<short8v*>(&Kn[krow * 256 + ((kch ^ kxor) + 8 * u) * 8]) = kreg[u];
            #pragma unroll
            for (int u = 0; u < 4; ++u)
                *reinterpret_cast<short8v*>(&Vn[tid * 32 + (u ^ vxor) * 8]) = vreg[u];
        }
        __syncthreads();   // single barrier per tile
    }

    // ---- epilogue ----
    float inv[4];
    #pragma unroll
    for (int g = 0; g < 4; ++g) {
        float l = lp[g];
        #pragma unroll
        for (int off = 1; off < 16; off <<= 1) l += __shfl_xor(l, off);
        inv[g] = 1.0f / l;
    }
    const float* imgS = img + (size_t)s * CDIM * HW;
    float*       outS = out + (size_t)s * CDIM * HW;
    const int tt = t0 + wave * 16 + 4 * hi4;
    #pragma unroll
    for (int cf = 0; cf < 16; ++cf) {
        const int c = cf * 16 + lo16;
        const float4 r4 = *reinterpret_cast<const float4*>(imgS + (size_t)c * HW + tt);
        float4 o;
        o.x = Oacc[cf][0] * inv[0] + r4.x;
        o.y = Oacc[cf][1] * inv[1] + r4.y;
        o.z = Oacc[cf][2] * inv[2] + r4.z;
        o.w = Oacc[cf][3] * inv[3] + r4.w;
        *reinterpret_cast<float4*>(outS + (size_t)c * HW + tt) = o;
    }
}

// ---------------------------------------------------------------------------
extern "C" void kernel_launch(void* const* d_in, const int* in_sizes, int n_in,
                              void* d_out, int out_size, void* d_ws, size_t ws_size,
                              hipStream_t stream)
{
    const float* img = (const float*)d_in[0];
    const float* dep = (const float*)d_in[1];
    const float* Wq  = (const float*)d_in[2];
    const float* bq  = (const float*)d_in[3];
    const float* Wk  = (const float*)d_in[4];
    const float* bk  = (const float*)d_in[5];
    const float* Wv  = (const float*)d_in[6];
    const float* bv  = (const float*)d_in[7];
    float* out = (float*)d_out;

    const size_t npt  = (size_t)NSLICE * HW * CDIM;
    const size_t need = 3 * npt * sizeof(bf16) + 3 * 65536 * sizeof(bf16);
    if (ws_size < need) {
        hipMemsetAsync(d_out, 0, (size_t)out_size * sizeof(float), stream);
        return;
    }

    bf16* q  = (bf16*)d_ws;        // token-major, prescaled
    bf16* k  = q + npt;            // token-major
    bf16* vt = k + npt;            // channel-major
    bf16* wt = vt + npt;           // [3][256][256] W^T

    hipFuncSetAttribute((const void*)flash_mfma_kernel,
                        hipFuncAttributeMaxDynamicSharedMemorySize,
                        FLASH_LDS_BYTES);

    wt_prep_kernel<<<dim3(3 * 256), 256, 0, stream>>>(Wq, Wk, Wv, wt);

    proj_q_kernel<<<dim3(NSLICE * 32), 256, 0, stream>>>(img, wt, bq, q);
    proj_kv_kernel<<<dim3(NSLICE * 32), 256, 0, stream>>>(dep, wt, bk, bv, k, vt);

    flash_mfma_kernel<<<dim3(NSLICE * 16), 256, FLASH_LDS_BYTES, stream>>>(
        q, k, vt, img, out);
}

// Round 18
// 122.882 us; speedup vs baseline: 1.0405x; 1.0405x over previous
//
#include <hip/hip_runtime.h>
#include <hip/hip_bf16.h>

typedef __hip_bfloat16 bf16;
typedef __attribute__((ext_vector_type(8))) short short8v;
typedef __attribute__((ext_vector_type(4))) float f32x4;

#define NSLICE 32   // B*S
#define HW     1024 // H*W
#define CDIM   256  // C1 == C2 == C
#define KVT    32   // kv tokens per flash inner tile
#define NKT    (HW / KVT)

// dynamic LDS layout (shorts): K0=0, K1=8192, V0=16384, V1=24576, Ps=32768
#define FLASH_LDS_BYTES ((32768 + 2048) * 2)

// ---------------------------------------------------------------------------
// Kernel 0: W^T prep. W f32 [cin][cout] -> wt bf16 [mat][cout][cin].
// Wq (mat 0) prescaled by 1/16.
// ---------------------------------------------------------------------------
__global__ __launch_bounds__(256)
void wt_prep_kernel(const float* __restrict__ Wq, const float* __restrict__ Wk,
                    const float* __restrict__ Wv, bf16* __restrict__ wt)
{
    const int m = blockIdx.x >> 8;
    const int r = blockIdx.x & 255;
    const int tid = threadIdx.x;
    const float* W = (m == 0) ? Wq : (m == 1) ? Wk : Wv;
    const float sc = (m == 0) ? 0.0625f : 1.0f;
    wt[((size_t)m << 16) + (size_t)tid * 256 + r] = __float2bfloat16(W[r * 256 + tid] * sc);
}

// ---------------------------------------------------------------------------
// Kernel 1a: Q projection (round-9 version: 16-row chunk staging with
// conflict-free [64][40] layout, register prefetch, 2 barriers/chunk).
// ---------------------------------------------------------------------------
__global__ __launch_bounds__(256)
void proj_q_kernel(const float* __restrict__ img, const bf16* __restrict__ wt,
                   const float* __restrict__ bq, bf16* __restrict__ qo)
{
    const int bid   = blockIdx.x;
    const int s     = (bid & 7) * 4 + ((bid >> 3) & 3);
    const int tt    = (bid >> 5) & 15;
    const int chalf = bid >> 9;
    const int t0    = tt * 64;

    const int tid  = threadIdx.x;
    const int wave = tid >> 6;
    const int lane = tid & 63;
    const int lo16 = lane & 15;
    const int hi4  = lane >> 4;
    const int cw0  = chalf * 128 + wave * 32;

    __shared__ short Ai[64][40];

    const int so = tid >> 6, st = tid & 63;
    const float* imgS = img + (size_t)s * CDIM * HW + t0;

    f32x4 aq[2][4];
    #pragma unroll
    for (int a = 0; a < 2; ++a)
        #pragma unroll
        for (int b = 0; b < 4; ++b) aq[a][b] = (f32x4){0.f, 0.f, 0.f, 0.f};

    float ri[8];
    #pragma unroll
    for (int j = 0; j < 8; ++j) ri[j] = imgS[(size_t)(so * 8 + j) * HW + st];

    for (int kc = 0; kc < 8; ++kc) {
        __syncthreads();
        {
            short ti[8];
            #pragma unroll
            for (int j = 0; j < 8; ++j) {
                bf16 hb = __float2bfloat16(ri[j]);
                ti[j] = *reinterpret_cast<short*>(&hb);
            }
            *reinterpret_cast<short8v*>(&Ai[st][so * 8]) = *reinterpret_cast<short8v*>(ti);
        }
        __syncthreads();

        if (kc < 7) {
            #pragma unroll
            for (int j = 0; j < 8; ++j)
                ri[j] = imgS[(size_t)((kc + 1) * 32 + so * 8 + j) * HW + st];
        }

        short8v xi[4];
        #pragma unroll
        for (int nf = 0; nf < 4; ++nf)
            xi[nf] = *reinterpret_cast<const short8v*>(&Ai[nf * 16 + lo16][hi4 * 8]);

        const int koff = kc * 32 + hi4 * 8;
        short8v wqf[2];
        #pragma unroll
        for (int mf = 0; mf < 2; ++mf)
            wqf[mf] = *reinterpret_cast<const short8v*>(
                wt + (size_t)(cw0 + mf * 16 + lo16) * 256 + koff);

        #pragma unroll
        for (int mf = 0; mf < 2; ++mf)
            #pragma unroll
            for (int nf = 0; nf < 4; ++nf)
                aq[mf][nf] = __builtin_amdgcn_mfma_f32_16x16x32_bf16(wqf[mf], xi[nf], aq[mf][nf], 0, 0, 0);
    }

    #pragma unroll
    for (int mf = 0; mf < 2; ++mf) {
        const int cb = cw0 + mf * 16 + 4 * hi4;
        const float4 b4 = *reinterpret_cast<const float4*>(bq + cb);
        const float ba[4] = {b4.x * 0.0625f, b4.y * 0.0625f, b4.z * 0.0625f, b4.w * 0.0625f};
        #pragma unroll
        for (int nf = 0; nf < 4; ++nf) {
            const int tok = t0 + nf * 16 + lo16;
            bf16 tq[4];
            #pragma unroll
            for (int g = 0; g < 4; ++g)
                tq[g] = __float2bfloat16(aq[mf][nf][g] + ba[g]);
            *reinterpret_cast<uint2*>(&qo[((size_t)s * HW + tok) * CDIM + cb]) =
                *reinterpret_cast<uint2*>(tq);
        }
    }
}

// ---------------------------------------------------------------------------
// Kernel 1b: K + V projection (round-9 version).
// ---------------------------------------------------------------------------
__global__ __launch_bounds__(256)
void proj_kv_kernel(const float* __restrict__ dep, const bf16* __restrict__ wt,
                    const float* __restrict__ bk, const float* __restrict__ bv,
                    bf16* __restrict__ ko, bf16* __restrict__ vt)
{
    const int bid   = blockIdx.x;
    const int s     = (bid & 7) * 4 + ((bid >> 3) & 3);
    const int tt    = (bid >> 5) & 15;
    const int chalf = bid >> 9;
    const int t0    = tt * 64;

    const int tid  = threadIdx.x;
    const int wave = tid >> 6;
    const int lane = tid & 63;
    const int lo16 = lane & 15;
    const int hi4  = lane >> 4;
    const int cw0  = chalf * 128 + wave * 32;

    __shared__ short Ad[64][40];

    const int so = tid >> 6, st = tid & 63;
    const float* depS = dep + (size_t)s * CDIM * HW + t0;
    const bf16* wtk = wt + (1 << 16);
    const bf16* wtv = wt + (2 << 16);

    f32x4 ak[2][4], av[4][2];
    #pragma unroll
    for (int a = 0; a < 2; ++a)
        #pragma unroll
        for (int b = 0; b < 4; ++b) {
            ak[a][b] = (f32x4){0.f, 0.f, 0.f, 0.f};
            av[b][a] = (f32x4){0.f, 0.f, 0.f, 0.f};
        }

    float rd[8];
    #pragma unroll
    for (int j = 0; j < 8; ++j) rd[j] = depS[(size_t)(so * 8 + j) * HW + st];

    for (int kc = 0; kc < 8; ++kc) {
        __syncthreads();
        {
            short td[8];
            #pragma unroll
            for (int j = 0; j < 8; ++j) {
                bf16 hb = __float2bfloat16(rd[j]);
                td[j] = *reinterpret_cast<short*>(&hb);
            }
            *reinterpret_cast<short8v*>(&Ad[st][so * 8]) = *reinterpret_cast<short8v*>(td);
        }
        __syncthreads();

        if (kc < 7) {
            #pragma unroll
            for (int j = 0; j < 8; ++j)
                rd[j] = depS[(size_t)((kc + 1) * 32 + so * 8 + j) * HW + st];
        }

        short8v xd[4];
        #pragma unroll
        for (int nf = 0; nf < 4; ++nf)
            xd[nf] = *reinterpret_cast<const short8v*>(&Ad[nf * 16 + lo16][hi4 * 8]);

        const int koff = kc * 32 + hi4 * 8;
        short8v wkf[2], wvf[2];
        #pragma unroll
        for (int mf = 0; mf < 2; ++mf) {
            const size_t wrow = (size_t)(cw0 + mf * 16 + lo16) * 256 + koff;
            wkf[mf] = *reinterpret_cast<const short8v*>(wtk + wrow);
            wvf[mf] = *reinterpret_cast<const short8v*>(wtv + wrow);
        }

        #pragma unroll
        for (int mf = 0; mf < 2; ++mf)
            #pragma unroll
            for (int nf = 0; nf < 4; ++nf)
                ak[mf][nf] = __builtin_amdgcn_mfma_f32_16x16x32_bf16(wkf[mf], xd[nf], ak[mf][nf], 0, 0, 0);
        #pragma unroll
        for (int mf = 0; mf < 4; ++mf)
            #pragma unroll
            for (int nf = 0; nf < 2; ++nf)
                av[mf][nf] = __builtin_amdgcn_mfma_f32_16x16x32_bf16(xd[mf], wvf[nf], av[mf][nf], 0, 0, 0);
    }

    #pragma unroll
    for (int mf = 0; mf < 2; ++mf) {
        const int cb = cw0 + mf * 16 + 4 * hi4;
        const float4 b4 = *reinterpret_cast<const float4*>(bk + cb);
        const float ba[4] = {b4.x, b4.y, b4.z, b4.w};
        #pragma unroll
        for (int nf = 0; nf < 4; ++nf) {
            const int tok = t0 + nf * 16 + lo16;
            bf16 tk[4];
            #pragma unroll
            for (int g = 0; g < 4; ++g)
                tk[g] = __float2bfloat16(ak[mf][nf][g] + ba[g]);
            *reinterpret_cast<uint2*>(&ko[((size_t)s * HW + tok) * CDIM + cb]) =
                *reinterpret_cast<uint2*>(tk);
        }
    }
    #pragma unroll
    for (int nf = 0; nf < 2; ++nf) {
        const int c = cw0 + nf * 16 + lo16;
        const float bvv = bv[c];
        #pragma unroll
        for (int mf = 0; mf < 4; ++mf) {
            const int tb = t0 + mf * 16 + 4 * hi4;
            bf16 tv[4];
            #pragma unroll
            for (int g = 0; g < 4; ++g)
                tv[g] = __float2bfloat16(av[mf][nf][g] + bvv);
            *reinterpret_cast<uint2*>(&vt[((size_t)s * CDIM + c) * HW + tb]) =
                *reinterpret_cast<uint2*>(tv);
        }
    }
}

// ---------------------------------------------------------------------------
// Kernel 2: MFMA flash attention (round-16 version: double-buffered K/V
// dynamic LDS, one barrier/tile, KVT=32, no-max softmax, XOR swizzles,
// register prefetch, setprio).
// ---------------------------------------------------------------------------
__global__ __launch_bounds__(256)
void flash_mfma_kernel(const bf16* __restrict__ q, const bf16* __restrict__ k,
                       const bf16* __restrict__ vt, const float* __restrict__ img,
                       float* __restrict__ out)
{
    const int bid = blockIdx.x;
    const int s   = (bid & 7) * 4 + ((bid >> 3) & 3);
    const int t0  = (bid >> 5) * 64;

    const int tid  = threadIdx.x;
    const int wave = tid >> 6;
    const int lane = tid & 63;
    const int lo16 = lane & 15;
    const int hi4  = lane >> 4;

    extern __shared__ short SM[];
    // K buffers at 0 / 8192, V buffers at 16384 / 24576, Ps at 32768

    short8v qf[8];
    {
        const bf16* qp = q + ((size_t)s * HW + t0 + wave * 16 + lo16) * CDIM + hi4 * 8;
        #pragma unroll
        for (int kf = 0; kf < 8; ++kf)
            qf[kf] = *reinterpret_cast<const short8v*>(qp + kf * 32);
    }

    f32x4 Oacc[16];
    #pragma unroll
    for (int cf = 0; cf < 16; ++cf) Oacc[cf] = (f32x4){0.f, 0.f, 0.f, 0.f};
    float lp[4] = {0.f, 0.f, 0.f, 0.f};

    const bf16* kS  = k  + (size_t)s * HW * CDIM;
    const bf16* vtS = vt + (size_t)s * CDIM * HW;

    const int krow = tid >> 3;
    const int kch  = tid & 7;
    const int kxor = krow & 7;
    const int vxor = (tid >> 1) & 3;

    short8v kreg[4], vreg[4];
    #pragma unroll
    for (int u = 0; u < 4; ++u) {
        kreg[u] = *reinterpret_cast<const short8v*>(kS + (size_t)krow * CDIM + (kch + 8 * u) * 8);
        vreg[u] = *reinterpret_cast<const short8v*>(vtS + (size_t)tid * HW + u * 8);
    }

    // prologue: publish tile 0 into buffer 0
    #pragma unroll
    for (int u = 0; u < 4; ++u)
        *reinterpret_cast<short8v*>(&SM[krow * 256 + ((kch ^ kxor) + 8 * u) * 8]) = kreg[u];
    #pragma unroll
    for (int u = 0; u < 4; ++u)
        *reinterpret_cast<short8v*>(&SM[16384 + tid * 32 + (u ^ vxor) * 8]) = vreg[u];
    __syncthreads();

    const int pvRow = lo16 * 32 + (hi4 ^ ((lo16 >> 1) & 3)) * 8;
    for (int kt = 0; kt < NKT; ++kt) {
        const int cur = kt & 1;
        const int nxt = cur ^ 1;
        short* Kc = SM + cur * 8192;
        short* Vc = SM + 16384 + cur * 8192;

        if (kt + 1 < NKT) {
            const bf16* src = kS + (size_t)(kt + 1) * KVT * CDIM;
            #pragma unroll
            for (int u = 0; u < 4; ++u) {
                kreg[u] = *reinterpret_cast<const short8v*>(src + (size_t)krow * CDIM + (kch + 8 * u) * 8);
                vreg[u] = *reinterpret_cast<const short8v*>(vtS + (size_t)tid * HW + (kt + 1) * KVT + u * 8);
            }
        }

        // ---- QK^T on current buffer ----
        f32x4 sa[2];
        sa[0] = (f32x4){0.f, 0.f, 0.f, 0.f};
        sa[1] = (f32x4){0.f, 0.f, 0.f, 0.f};
        __builtin_amdgcn_s_setprio(1);
        #pragma unroll
        for (int ks = 0; ks < 8; ++ks) {
            #pragma unroll
            for (int cf = 0; cf < 2; ++cf) {
                const int row = cf * 16 + lo16;
                short8v bfr = *reinterpret_cast<const short8v*>(
                    &Kc[row * 256 + ((4 * ks + hi4) ^ (lo16 & 7)) * 8]);
                sa[cf] = __builtin_amdgcn_mfma_f32_16x16x32_bf16(qf[ks], bfr, sa[cf], 0, 0, 0);
            }
        }
        __builtin_amdgcn_s_setprio(0);

        // ---- P = exp(S); lane-local l partials; P -> LDS swizzled ----
        #pragma unroll
        for (int cf = 0; cf < 2; ++cf)
            #pragma unroll
            for (int g = 0; g < 4; ++g) {
                const float e = __expf(sa[cf][g]);
                lp[g] += e;
                bf16 hb = __float2bfloat16(e);
                const int r = 4 * hi4 + g;
                const int ch = (2 * cf + (lo16 >> 3)) ^ ((r >> 1) & 3);
                SM[32768 + wave * 512 + r * 32 + ch * 8 + (lo16 & 7)] = *reinterpret_cast<short*>(&hb);
            }

        const short8v pa = *reinterpret_cast<const short8v*>(&SM[32768 + wave * 512 + pvRow]);

        // ---- PV on current buffer ----
        __builtin_amdgcn_s_setprio(1);
        #pragma unroll
        for (int cf = 0; cf < 16; ++cf) {
            const int row = cf * 16 + lo16;
            const short8v vb = *reinterpret_cast<const short8v*>(
                &Vc[row * 32 + (hi4 ^ ((lo16 >> 1) & 3)) * 8]);
            Oacc[cf] = __builtin_amdgcn_mfma_f32_16x16x32_bf16(pa, vb, Oacc[cf], 0, 0, 0);
        }
        __builtin_amdgcn_s_setprio(0);

        // ---- publish tile kt+1 into the idle buffer ----
        if (kt + 1 < NKT) {
            short* Kn = SM + nxt * 8192;
            short* Vn = SM + 16384 + nxt * 8192;
            #pragma unroll
            for (int u = 0; u < 4; ++u)
                *reinterpret_cast<short8v*>(&Kn[krow * 256 + ((kch ^ kxor) + 8 * u) * 8]) = kreg[u];
            #pragma unroll
            for (int u = 0; u < 4; ++u)
                *reinterpret_cast<short8v*>(&Vn[tid * 32 + (u ^ vxor) * 8]) = vreg[u];
        }
        __syncthreads();   // single barrier per tile
    }

    // ---- epilogue ----
    float inv[4];
    #pragma unroll
    for (int g = 0; g < 4; ++g) {
        float l = lp[g];
        #pragma unroll
        for (int off = 1; off < 16; off <<= 1) l += __shfl_xor(l, off);
        inv[g] = 1.0f / l;
    }
    const float* imgS = img + (size_t)s * CDIM * HW;
    float*       outS = out + (size_t)s * CDIM * HW;
    const int tt = t0 + wave * 16 + 4 * hi4;
    #pragma unroll
    for (int cf = 0; cf < 16; ++cf) {
        const int c = cf * 16 + lo16;
        const float4 r4 = *reinterpret_cast<const float4*>(imgS + (size_t)c * HW + tt);
        float4 o;
        o.x = Oacc[cf][0] * inv[0] + r4.x;
        o.y = Oacc[cf][1] * inv[1] + r4.y;
        o.z = Oacc[cf][2] * inv[2] + r4.z;
        o.w = Oacc[cf][3] * inv[3] + r4.w;
        *reinterpret_cast<float4*>(outS + (size_t)c * HW + tt) = o;
    }
}

// ---------------------------------------------------------------------------
extern "C" void kernel_launch(void* const* d_in, const int* in_sizes, int n_in,
                              void* d_out, int out_size, void* d_ws, size_t ws_size,
                              hipStream_t stream)
{
    const float* img = (const float*)d_in[0];
    const float* dep = (const float*)d_in[1];
    const float* Wq  = (const float*)d_in[2];
    const float* bq  = (const float*)d_in[3];
    const float* Wk  = (const float*)d_in[4];
    const float* bk  = (const float*)d_in[5];
    const float* Wv  = (const float*)d_in[6];
    const float* bv  = (const float*)d_in[7];
    float* out = (float*)d_out;

    const size_t npt  = (size_t)NSLICE * HW * CDIM;
    const size_t need = 3 * npt * sizeof(bf16) + 3 * 65536 * sizeof(bf16);
    if (ws_size < need) {
        hipMemsetAsync(d_out, 0, (size_t)out_size * sizeof(float), stream);
        return;
    }

    bf16* q  = (bf16*)d_ws;        // token-major, prescaled
    bf16* k  = q + npt;            // token-major
    bf16* vt = k + npt;            // channel-major
    bf16* wt = vt + npt;           // [3][256][256] W^T

    hipFuncSetAttribute((const void*)flash_mfma_kernel,
                        hipFuncAttributeMaxDynamicSharedMemorySize,
                        FLASH_LDS_BYTES);

    wt_prep_kernel<<<dim3(3 * 256), 256, 0, stream>>>(Wq, Wk, Wv, wt);

    proj_q_kernel<<<dim3(NSLICE * 32), 256, 0, stream>>>(img, wt, bq, q);
    proj_kv_kernel<<<dim3(NSLICE * 32), 256, 0, stream>>>(dep, wt, bk, bv, k, vt);

    flash_mfma_kernel<<<dim3(NSLICE * 16), 256, FLASH_LDS_BYTES, stream>>>(
        q, k, vt, img, out);
}

// Round 19
// 122.455 us; speedup vs baseline: 1.0441x; 1.0035x over previous
//
#include <hip/hip_runtime.h>
#include <hip/hip_bf16.h>

typedef __hip_bfloat16 bf16;
typedef __attribute__((ext_vector_type(8))) short short8v;
typedef __attribute__((ext_vector_type(4))) float f32x4;

#define NSLICE 32   // B*S
#define HW     1024 // H*W
#define CDIM   256  // C1 == C2 == C
#define KVT    32   // kv tokens per flash inner tile
#define NKT    (HW / KVT)

// dynamic LDS layout (shorts): K0=0, K1=8192, V0=16384, V1=24576, Ps=32768
#define FLASH_LDS_BYTES ((32768 + 2048) * 2)

// ---------------------------------------------------------------------------
// Kernel 0: W^T prep. W f32 [cin][cout] -> wt bf16 [mat][cout][cin].
// Wq (mat 0) prescaled by 1/16.
// ---------------------------------------------------------------------------
__global__ __launch_bounds__(256)
void wt_prep_kernel(const float* __restrict__ Wq, const float* __restrict__ Wk,
                    const float* __restrict__ Wv, bf16* __restrict__ wt)
{
    const int m = blockIdx.x >> 8;
    const int r = blockIdx.x & 255;
    const int tid = threadIdx.x;
    const float* W = (m == 0) ? Wq : (m == 1) ? Wk : Wv;
    const float sc = (m == 0) ? 0.0625f : 1.0f;
    wt[((size_t)m << 16) + (size_t)tid * 256 + r] = __float2bfloat16(W[r * 256 + tid] * sc);
}

// ---------------------------------------------------------------------------
// Kernel 1a: Q projection (round-9 version: 16-row chunk staging with
// conflict-free [64][40] layout, register prefetch, 2 barriers/chunk).
// ---------------------------------------------------------------------------
__global__ __launch_bounds__(256)
void proj_q_kernel(const float* __restrict__ img, const bf16* __restrict__ wt,
                   const float* __restrict__ bq, bf16* __restrict__ qo)
{
    const int bid   = blockIdx.x;
    const int s     = (bid & 7) * 4 + ((bid >> 3) & 3);
    const int tt    = (bid >> 5) & 15;
    const int chalf = bid >> 9;
    const int t0    = tt * 64;

    const int tid  = threadIdx.x;
    const int wave = tid >> 6;
    const int lane = tid & 63;
    const int lo16 = lane & 15;
    const int hi4  = lane >> 4;
    const int cw0  = chalf * 128 + wave * 32;

    __shared__ short Ai[64][40];

    const int so = tid >> 6, st = tid & 63;
    const float* imgS = img + (size_t)s * CDIM * HW + t0;

    f32x4 aq[2][4];
    #pragma unroll
    for (int a = 0; a < 2; ++a)
        #pragma unroll
        for (int b = 0; b < 4; ++b) aq[a][b] = (f32x4){0.f, 0.f, 0.f, 0.f};

    float ri[8];
    #pragma unroll
    for (int j = 0; j < 8; ++j) ri[j] = imgS[(size_t)(so * 8 + j) * HW + st];

    for (int kc = 0; kc < 8; ++kc) {
        __syncthreads();
        {
            short ti[8];
            #pragma unroll
            for (int j = 0; j < 8; ++j) {
                bf16 hb = __float2bfloat16(ri[j]);
                ti[j] = *reinterpret_cast<short*>(&hb);
            }
            *reinterpret_cast<short8v*>(&Ai[st][so * 8]) = *reinterpret_cast<short8v*>(ti);
        }
        __syncthreads();

        if (kc < 7) {
            #pragma unroll
            for (int j = 0; j < 8; ++j)
                ri[j] = imgS[(size_t)((kc + 1) * 32 + so * 8 + j) * HW + st];
        }

        short8v xi[4];
        #pragma unroll
        for (int nf = 0; nf < 4; ++nf)
            xi[nf] = *reinterpret_cast<const short8v*>(&Ai[nf * 16 + lo16][hi4 * 8]);

        const int koff = kc * 32 + hi4 * 8;
        short8v wqf[2];
        #pragma unroll
        for (int mf = 0; mf < 2; ++mf)
            wqf[mf] = *reinterpret_cast<const short8v*>(
                wt + (size_t)(cw0 + mf * 16 + lo16) * 256 + koff);

        #pragma unroll
        for (int mf = 0; mf < 2; ++mf)
            #pragma unroll
            for (int nf = 0; nf < 4; ++nf)
                aq[mf][nf] = __builtin_amdgcn_mfma_f32_16x16x32_bf16(wqf[mf], xi[nf], aq[mf][nf], 0, 0, 0);
    }

    #pragma unroll
    for (int mf = 0; mf < 2; ++mf) {
        const int cb = cw0 + mf * 16 + 4 * hi4;
        const float4 b4 = *reinterpret_cast<const float4*>(bq + cb);
        const float ba[4] = {b4.x * 0.0625f, b4.y * 0.0625f, b4.z * 0.0625f, b4.w * 0.0625f};
        #pragma unroll
        for (int nf = 0; nf < 4; ++nf) {
            const int tok = t0 + nf * 16 + lo16;
            bf16 tq[4];
            #pragma unroll
            for (int g = 0; g < 4; ++g)
                tq[g] = __float2bfloat16(aq[mf][nf][g] + ba[g]);
            *reinterpret_cast<uint2*>(&qo[((size_t)s * HW + tok) * CDIM + cb]) =
                *reinterpret_cast<uint2*>(tq);
        }
    }
}

// ---------------------------------------------------------------------------
// Kernel 1b: K + V projection (round-9 version).
// ---------------------------------------------------------------------------
__global__ __launch_bounds__(256)
void proj_kv_kernel(const float* __restrict__ dep, const bf16* __restrict__ wt,
                    const float* __restrict__ bk, const float* __restrict__ bv,
                    bf16* __restrict__ ko, bf16* __restrict__ vt)
{
    const int bid   = blockIdx.x;
    const int s     = (bid & 7) * 4 + ((bid >> 3) & 3);
    const int tt    = (bid >> 5) & 15;
    const int chalf = bid >> 9;
    const int t0    = tt * 64;

    const int tid  = threadIdx.x;
    const int wave = tid >> 6;
    const int lane = tid & 63;
    const int lo16 = lane & 15;
    const int hi4  = lane >> 4;
    const int cw0  = chalf * 128 + wave * 32;

    __shared__ short Ad[64][40];

    const int so = tid >> 6, st = tid & 63;
    const float* depS = dep + (size_t)s * CDIM * HW + t0;
    const bf16* wtk = wt + (1 << 16);
    const bf16* wtv = wt + (2 << 16);

    f32x4 ak[2][4], av[4][2];
    #pragma unroll
    for (int a = 0; a < 2; ++a)
        #pragma unroll
        for (int b = 0; b < 4; ++b) {
            ak[a][b] = (f32x4){0.f, 0.f, 0.f, 0.f};
            av[b][a] = (f32x4){0.f, 0.f, 0.f, 0.f};
        }

    float rd[8];
    #pragma unroll
    for (int j = 0; j < 8; ++j) rd[j] = depS[(size_t)(so * 8 + j) * HW + st];

    for (int kc = 0; kc < 8; ++kc) {
        __syncthreads();
        {
            short td[8];
            #pragma unroll
            for (int j = 0; j < 8; ++j) {
                bf16 hb = __float2bfloat16(rd[j]);
                td[j] = *reinterpret_cast<short*>(&hb);
            }
            *reinterpret_cast<short8v*>(&Ad[st][so * 8]) = *reinterpret_cast<short8v*>(td);
        }
        __syncthreads();

        if (kc < 7) {
            #pragma unroll
            for (int j = 0; j < 8; ++j)
                rd[j] = depS[(size_t)((kc + 1) * 32 + so * 8 + j) * HW + st];
        }

        short8v xd[4];
        #pragma unroll
        for (int nf = 0; nf < 4; ++nf)
            xd[nf] = *reinterpret_cast<const short8v*>(&Ad[nf * 16 + lo16][hi4 * 8]);

        const int koff = kc * 32 + hi4 * 8;
        short8v wkf[2], wvf[2];
        #pragma unroll
        for (int mf = 0; mf < 2; ++mf) {
            const size_t wrow = (size_t)(cw0 + mf * 16 + lo16) * 256 + koff;
            wkf[mf] = *reinterpret_cast<const short8v*>(wtk + wrow);
            wvf[mf] = *reinterpret_cast<const short8v*>(wtv + wrow);
        }

        #pragma unroll
        for (int mf = 0; mf < 2; ++mf)
            #pragma unroll
            for (int nf = 0; nf < 4; ++nf)
                ak[mf][nf] = __builtin_amdgcn_mfma_f32_16x16x32_bf16(wkf[mf], xd[nf], ak[mf][nf], 0, 0, 0);
        #pragma unroll
        for (int mf = 0; mf < 4; ++mf)
            #pragma unroll
            for (int nf = 0; nf < 2; ++nf)
                av[mf][nf] = __builtin_amdgcn_mfma_f32_16x16x32_bf16(xd[mf], wvf[nf], av[mf][nf], 0, 0, 0);
    }

    #pragma unroll
    for (int mf = 0; mf < 2; ++mf) {
        const int cb = cw0 + mf * 16 + 4 * hi4;
        const float4 b4 = *reinterpret_cast<const float4*>(bk + cb);
        const float ba[4] = {b4.x, b4.y, b4.z, b4.w};
        #pragma unroll
        for (int nf = 0; nf < 4; ++nf) {
            const int tok = t0 + nf * 16 + lo16;
            bf16 tk[4];
            #pragma unroll
            for (int g = 0; g < 4; ++g)
                tk[g] = __float2bfloat16(ak[mf][nf][g] + ba[g]);
            *reinterpret_cast<uint2*>(&ko[((size_t)s * HW + tok) * CDIM + cb]) =
                *reinterpret_cast<uint2*>(tk);
        }
    }
    #pragma unroll
    for (int nf = 0; nf < 2; ++nf) {
        const int c = cw0 + nf * 16 + lo16;
        const float bvv = bv[c];
        #pragma unroll
        for (int mf = 0; mf < 4; ++mf) {
            const int tb = t0 + mf * 16 + 4 * hi4;
            bf16 tv[4];
            #pragma unroll
            for (int g = 0; g < 4; ++g)
                tv[g] = __float2bfloat16(av[mf][nf][g] + bvv);
            *reinterpret_cast<uint2*>(&vt[((size_t)s * CDIM + c) * HW + tb]) =
                *reinterpret_cast<uint2*>(tv);
        }
    }
}

// ---------------------------------------------------------------------------
// Kernel 2: MFMA flash attention (round-16 version: double-buffered K/V
// dynamic LDS, one barrier/tile, KVT=32, no-max softmax, XOR swizzles,
// register prefetch, setprio).
// ---------------------------------------------------------------------------
__global__ __launch_bounds__(256)
void flash_mfma_kernel(const bf16* __restrict__ q, const bf16* __restrict__ k,
                       const bf16* __restrict__ vt, const float* __restrict__ img,
                       float* __restrict__ out)
{
    const int bid = blockIdx.x;
    const int s   = (bid & 7) * 4 + ((bid >> 3) & 3);
    const int t0  = (bid >> 5) * 64;

    const int tid  = threadIdx.x;
    const int wave = tid >> 6;
    const int lane = tid & 63;
    const int lo16 = lane & 15;
    const int hi4  = lane >> 4;

    extern __shared__ short SM[];
    // K buffers at 0 / 8192, V buffers at 16384 / 24576, Ps at 32768

    short8v qf[8];
    {
        const bf16* qp = q + ((size_t)s * HW + t0 + wave * 16 + lo16) * CDIM + hi4 * 8;
        #pragma unroll
        for (int kf = 0; kf < 8; ++kf)
            qf[kf] = *reinterpret_cast<const short8v*>(qp + kf * 32);
    }

    f32x4 Oacc[16];
    #pragma unroll
    for (int cf = 0; cf < 16; ++cf) Oacc[cf] = (f32x4){0.f, 0.f, 0.f, 0.f};
    float lp[4] = {0.f, 0.f, 0.f, 0.f};

    const bf16* kS  = k  + (size_t)s * HW * CDIM;
    const bf16* vtS = vt + (size_t)s * CDIM * HW;

    const int krow = tid >> 3;
    const int kch  = tid & 7;
    const int kxor = krow & 7;
    const int vxor = (tid >> 1) & 3;

    short8v kreg[4], vreg[4];
    #pragma unroll
    for (int u = 0; u < 4; ++u) {
        kreg[u] = *reinterpret_cast<const short8v*>(kS + (size_t)krow * CDIM + (kch + 8 * u) * 8);
        vreg[u] = *reinterpret_cast<const short8v*>(vtS + (size_t)tid * HW + u * 8);
    }

    // prologue: publish tile 0 into buffer 0
    #pragma unroll
    for (int u = 0; u < 4; ++u)
        *reinterpret_cast<short8v*>(&SM[krow * 256 + ((kch ^ kxor) + 8 * u) * 8]) = kreg[u];
    #pragma unroll
    for (int u = 0; u < 4; ++u)
        *reinterpret_cast<short8v*>(&SM[16384 + tid * 32 + (u ^ vxor) * 8]) = vreg[u];
    __syncthreads();

    const int pvRow = lo16 * 32 + (hi4 ^ ((lo16 >> 1) & 3)) * 8;
    for (int kt = 0; kt < NKT; ++kt) {
        const int cur = kt & 1;
        const int nxt = cur ^ 1;
        short* Kc = SM + cur * 8192;
        short* Vc = SM + 16384 + cur * 8192;

        if (kt + 1 < NKT) {
            const bf16* src = kS + (size_t)(kt + 1) * KVT * CDIM;
            #pragma unroll
            for (int u = 0; u < 4; ++u) {
                kreg[u] = *reinterpret_cast<const short8v*>(src + (size_t)krow * CDIM + (kch + 8 * u) * 8);
                vreg[u] = *reinterpret_cast<const short8v*>(vtS + (size_t)tid * HW + (kt + 1) * KVT + u * 8);
            }
        }

        // ---- QK^T on current buffer ----
        f32x4 sa[2];
        sa[0] = (f32x4){0.f, 0.f, 0.f, 0.f};
        sa[1] = (f32x4){0.f, 0.f, 0.f, 0.f};
        __builtin_amdgcn_s_setprio(1);
        #pragma unroll
        for (int ks = 0; ks < 8; ++ks) {
            #pragma unroll
            for (int cf = 0; cf < 2; ++cf) {
                const int row = cf * 16 + lo16;
                short8v bfr = *reinterpret_cast<const short8v*>(
                    &Kc[row * 256 + ((4 * ks + hi4) ^ (lo16 & 7)) * 8]);
                sa[cf] = __builtin_amdgcn_mfma_f32_16x16x32_bf16(qf[ks], bfr, sa[cf], 0, 0, 0);
            }
        }
        __builtin_amdgcn_s_setprio(0);

        // ---- P = exp(S); lane-local l partials; P -> LDS swizzled ----
        #pragma unroll
        for (int cf = 0; cf < 2; ++cf)
            #pragma unroll
            for (int g = 0; g < 4; ++g) {
                const float e = __expf(sa[cf][g]);
                lp[g] += e;
                bf16 hb = __float2bfloat16(e);
                const int r = 4 * hi4 + g;
                const int ch = (2 * cf + (lo16 >> 3)) ^ ((r >> 1) & 3);
                SM[32768 + wave * 512 + r * 32 + ch * 8 + (lo16 & 7)] = *reinterpret_cast<short*>(&hb);
            }

        const short8v pa = *reinterpret_cast<const short8v*>(&SM[32768 + wave * 512 + pvRow]);

        // ---- PV on current buffer ----
        __builtin_amdgcn_s_setprio(1);
        #pragma unroll
        for (int cf = 0; cf < 16; ++cf) {
            const int row = cf * 16 + lo16;
            const short8v vb = *reinterpret_cast<const short8v*>(
                &Vc[row * 32 + (hi4 ^ ((lo16 >> 1) & 3)) * 8]);
            Oacc[cf] = __builtin_amdgcn_mfma_f32_16x16x32_bf16(pa, vb, Oacc[cf], 0, 0, 0);
        }
        __builtin_amdgcn_s_setprio(0);

        // ---- publish tile kt+1 into the idle buffer ----
        if (kt + 1 < NKT) {
            short* Kn = SM + nxt * 8192;
            short* Vn = SM + 16384 + nxt * 8192;
            #pragma unroll
            for (int u = 0; u < 4; ++u)
                *reinterpret_cast<short8v*>(&Kn[krow * 256 + ((kch ^ kxor) + 8 * u) * 8]) = kreg[u];
            #pragma unroll
            for (int u = 0; u < 4; ++u)
                *reinterpret_cast<short8v*>(&Vn[tid * 32 + (u ^ vxor) * 8]) = vreg[u];
        }
        __syncthreads();   // single barrier per tile
    }

    // ---- epilogue ----
    float inv[4];
    #pragma unroll
    for (int g = 0; g < 4; ++g) {
        float l = lp[g];
        #pragma unroll
        for (int off = 1; off < 16; off <<= 1) l += __shfl_xor(l, off);
        inv[g] = 1.0f / l;
    }
    const float* imgS = img + (size_t)s * CDIM * HW;
    float*       outS = out + (size_t)s * CDIM * HW;
    const int tt = t0 + wave * 16 + 4 * hi4;
    #pragma unroll
    for (int cf = 0; cf < 16; ++cf) {
        const int c = cf * 16 + lo16;
        const float4 r4 = *reinterpret_cast<const float4*>(imgS + (size_t)c * HW + tt);
        float4 o;
        o.x = Oacc[cf][0] * inv[0] + r4.x;
        o.y = Oacc[cf][1] * inv[1] + r4.y;
        o.z = Oacc[cf][2] * inv[2] + r4.z;
        o.w = Oacc[cf][3] * inv[3] + r4.w;
        *reinterpret_cast<float4*>(outS + (size_t)c * HW + tt) = o;
    }
}

// ---------------------------------------------------------------------------
extern "C" void kernel_launch(void* const* d_in, const int* in_sizes, int n_in,
                              void* d_out, int out_size, void* d_ws, size_t ws_size,
                              hipStream_t stream)
{
    const float* img = (const float*)d_in[0];
    const float* dep = (const float*)d_in[1];
    const float* Wq  = (const float*)d_in[2];
    const float* bq  = (const float*)d_in[3];
    const float* Wk  = (const float*)d_in[4];
    const float* bk  = (const float*)d_in[5];
    const float* Wv  = (const float*)d_in[6];
    const float* bv  = (const float*)d_in[7];
    float* out = (float*)d_out;

    const size_t npt  = (size_t)NSLICE * HW * CDIM;
    const size_t need = 3 * npt * sizeof(bf16) + 3 * 65536 * sizeof(bf16);
    if (ws_size < need) {
        hipMemsetAsync(d_out, 0, (size_t)out_size * sizeof(float), stream);
        return;
    }

    bf16* q  = (bf16*)d_ws;        // token-major, prescaled
    bf16* k  = q + npt;            // token-major
    bf16* vt = k + npt;            // channel-major
    bf16* wt = vt + npt;           // [3][256][256] W^T

    hipFuncSetAttribute((const void*)flash_mfma_kernel,
                        hipFuncAttributeMaxDynamicSharedMemorySize,
                        FLASH_LDS_BYTES);

    wt_prep_kernel<<<dim3(3 * 256), 256, 0, stream>>>(Wq, Wk, Wv, wt);

    proj_q_kernel<<<dim3(NSLICE * 32), 256, 0, stream>>>(img, wt, bq, q);
    proj_kv_kernel<<<dim3(NSLICE * 32), 256, 0, stream>>>(dep, wt, bk, bv, k, vt);

    flash_mfma_kernel<<<dim3(NSLICE * 16), 256, FLASH_LDS_BYTES, stream>>>(
        q, k, vt, img, out);
}

// Round 20
// 120.813 us; speedup vs baseline: 1.0583x; 1.0136x over previous
//
#include <hip/hip_runtime.h>
#include <hip/hip_bf16.h>

typedef __hip_bfloat16 bf16;
typedef __attribute__((ext_vector_type(8))) short short8v;
typedef __attribute__((ext_vector_type(4))) float f32x4;

#define NSLICE 32   // B*S
#define HW     1024 // H*W
#define CDIM   256  // C1 == C2 == C
#define KVT    32   // kv tokens per flash inner tile
#define NKT    (HW / KVT)

// dynamic LDS layout (shorts): K0=0, K1=8192, V0=16384, V1=24576, Ps=32768
#define FLASH_LDS_BYTES ((32768 + 2048) * 2)

// async 16B global->LDS (wave-uniform LDS base + lane*16B; per-lane gsrc)
__device__ __forceinline__ void gl_lds16(const void* g, void* l) {
    __builtin_amdgcn_global_load_lds(
        (const __attribute__((address_space(1))) unsigned int*)g,
        (__attribute__((address_space(3))) unsigned int*)l,
        16, 0, 0);
}

// ---------------------------------------------------------------------------
// Kernel 0: W^T prep. W f32 [cin][cout] -> wt bf16 [mat][cout][cin].
// Wq (mat 0) prescaled by 1/16.
// ---------------------------------------------------------------------------
__global__ __launch_bounds__(256)
void wt_prep_kernel(const float* __restrict__ Wq, const float* __restrict__ Wk,
                    const float* __restrict__ Wv, bf16* __restrict__ wt)
{
    const int m = blockIdx.x >> 8;
    const int r = blockIdx.x & 255;
    const int tid = threadIdx.x;
    const float* W = (m == 0) ? Wq : (m == 1) ? Wk : Wv;
    const float sc = (m == 0) ? 0.0625f : 1.0f;
    wt[((size_t)m << 16) + (size_t)tid * 256 + r] = __float2bfloat16(W[r * 256 + tid] * sc);
}

// ---------------------------------------------------------------------------
// Kernel 1a: Q projection (round-9 version).
// ---------------------------------------------------------------------------
__global__ __launch_bounds__(256)
void proj_q_kernel(const float* __restrict__ img, const bf16* __restrict__ wt,
                   const float* __restrict__ bq, bf16* __restrict__ qo)
{
    const int bid   = blockIdx.x;
    const int s     = (bid & 7) * 4 + ((bid >> 3) & 3);
    const int tt    = (bid >> 5) & 15;
    const int chalf = bid >> 9;
    const int t0    = tt * 64;

    const int tid  = threadIdx.x;
    const int wave = tid >> 6;
    const int lane = tid & 63;
    const int lo16 = lane & 15;
    const int hi4  = lane >> 4;
    const int cw0  = chalf * 128 + wave * 32;

    __shared__ short Ai[64][40];

    const int so = tid >> 6, st = tid & 63;
    const float* imgS = img + (size_t)s * CDIM * HW + t0;

    f32x4 aq[2][4];
    #pragma unroll
    for (int a = 0; a < 2; ++a)
        #pragma unroll
        for (int b = 0; b < 4; ++b) aq[a][b] = (f32x4){0.f, 0.f, 0.f, 0.f};

    float ri[8];
    #pragma unroll
    for (int j = 0; j < 8; ++j) ri[j] = imgS[(size_t)(so * 8 + j) * HW + st];

    for (int kc = 0; kc < 8; ++kc) {
        __syncthreads();
        {
            short ti[8];
            #pragma unroll
            for (int j = 0; j < 8; ++j) {
                bf16 hb = __float2bfloat16(ri[j]);
                ti[j] = *reinterpret_cast<short*>(&hb);
            }
            *reinterpret_cast<short8v*>(&Ai[st][so * 8]) = *reinterpret_cast<short8v*>(ti);
        }
        __syncthreads();

        if (kc < 7) {
            #pragma unroll
            for (int j = 0; j < 8; ++j)
                ri[j] = imgS[(size_t)((kc + 1) * 32 + so * 8 + j) * HW + st];
        }

        short8v xi[4];
        #pragma unroll
        for (int nf = 0; nf < 4; ++nf)
            xi[nf] = *reinterpret_cast<const short8v*>(&Ai[nf * 16 + lo16][hi4 * 8]);

        const int koff = kc * 32 + hi4 * 8;
        short8v wqf[2];
        #pragma unroll
        for (int mf = 0; mf < 2; ++mf)
            wqf[mf] = *reinterpret_cast<const short8v*>(
                wt + (size_t)(cw0 + mf * 16 + lo16) * 256 + koff);

        #pragma unroll
        for (int mf = 0; mf < 2; ++mf)
            #pragma unroll
            for (int nf = 0; nf < 4; ++nf)
                aq[mf][nf] = __builtin_amdgcn_mfma_f32_16x16x32_bf16(wqf[mf], xi[nf], aq[mf][nf], 0, 0, 0);
    }

    #pragma unroll
    for (int mf = 0; mf < 2; ++mf) {
        const int cb = cw0 + mf * 16 + 4 * hi4;
        const float4 b4 = *reinterpret_cast<const float4*>(bq + cb);
        const float ba[4] = {b4.x * 0.0625f, b4.y * 0.0625f, b4.z * 0.0625f, b4.w * 0.0625f};
        #pragma unroll
        for (int nf = 0; nf < 4; ++nf) {
            const int tok = t0 + nf * 16 + lo16;
            bf16 tq[4];
            #pragma unroll
            for (int g = 0; g < 4; ++g)
                tq[g] = __float2bfloat16(aq[mf][nf][g] + ba[g]);
            *reinterpret_cast<uint2*>(&qo[((size_t)s * HW + tok) * CDIM + cb]) =
                *reinterpret_cast<uint2*>(tq);
        }
    }
}

// ---------------------------------------------------------------------------
// Kernel 1b: K + V projection (round-9 version).
// ---------------------------------------------------------------------------
__global__ __launch_bounds__(256)
void proj_kv_kernel(const float* __restrict__ dep, const bf16* __restrict__ wt,
                    const float* __restrict__ bk, const float* __restrict__ bv,
                    bf16* __restrict__ ko, bf16* __restrict__ vt)
{
    const int bid   = blockIdx.x;
    const int s     = (bid & 7) * 4 + ((bid >> 3) & 3);
    const int tt    = (bid >> 5) & 15;
    const int chalf = bid >> 9;
    const int t0    = tt * 64;

    const int tid  = threadIdx.x;
    const int wave = tid >> 6;
    const int lane = tid & 63;
    const int lo16 = lane & 15;
    const int hi4  = lane >> 4;
    const int cw0  = chalf * 128 + wave * 32;

    __shared__ short Ad[64][40];

    const int so = tid >> 6, st = tid & 63;
    const float* depS = dep + (size_t)s * CDIM * HW + t0;
    const bf16* wtk = wt + (1 << 16);
    const bf16* wtv = wt + (2 << 16);

    f32x4 ak[2][4], av[4][2];
    #pragma unroll
    for (int a = 0; a < 2; ++a)
        #pragma unroll
        for (int b = 0; b < 4; ++b) {
            ak[a][b] = (f32x4){0.f, 0.f, 0.f, 0.f};
            av[b][a] = (f32x4){0.f, 0.f, 0.f, 0.f};
        }

    float rd[8];
    #pragma unroll
    for (int j = 0; j < 8; ++j) rd[j] = depS[(size_t)(so * 8 + j) * HW + st];

    for (int kc = 0; kc < 8; ++kc) {
        __syncthreads();
        {
            short td[8];
            #pragma unroll
            for (int j = 0; j < 8; ++j) {
                bf16 hb = __float2bfloat16(rd[j]);
                td[j] = *reinterpret_cast<short*>(&hb);
            }
            *reinterpret_cast<short8v*>(&Ad[st][so * 8]) = *reinterpret_cast<short8v*>(td);
        }
        __syncthreads();

        if (kc < 7) {
            #pragma unroll
            for (int j = 0; j < 8; ++j)
                rd[j] = depS[(size_t)((kc + 1) * 32 + so * 8 + j) * HW + st];
        }

        short8v xd[4];
        #pragma unroll
        for (int nf = 0; nf < 4; ++nf)
            xd[nf] = *reinterpret_cast<const short8v*>(&Ad[nf * 16 + lo16][hi4 * 8]);

        const int koff = kc * 32 + hi4 * 8;
        short8v wkf[2], wvf[2];
        #pragma unroll
        for (int mf = 0; mf < 2; ++mf) {
            const size_t wrow = (size_t)(cw0 + mf * 16 + lo16) * 256 + koff;
            wkf[mf] = *reinterpret_cast<const short8v*>(wtk + wrow);
            wvf[mf] = *reinterpret_cast<const short8v*>(wtv + wrow);
        }

        #pragma unroll
        for (int mf = 0; mf < 2; ++mf)
            #pragma unroll
            for (int nf = 0; nf < 4; ++nf)
                ak[mf][nf] = __builtin_amdgcn_mfma_f32_16x16x32_bf16(wkf[mf], xd[nf], ak[mf][nf], 0, 0, 0);
        #pragma unroll
        for (int mf = 0; mf < 4; ++mf)
            #pragma unroll
            for (int nf = 0; nf < 2; ++nf)
                av[mf][nf] = __builtin_amdgcn_mfma_f32_16x16x32_bf16(xd[mf], wvf[nf], av[mf][nf], 0, 0, 0);
    }

    #pragma unroll
    for (int mf = 0; mf < 2; ++mf) {
        const int cb = cw0 + mf * 16 + 4 * hi4;
        const float4 b4 = *reinterpret_cast<const float4*>(bk + cb);
        const float ba[4] = {b4.x, b4.y, b4.z, b4.w};
        #pragma unroll
        for (int nf = 0; nf < 4; ++nf) {
            const int tok = t0 + nf * 16 + lo16;
            bf16 tk[4];
            #pragma unroll
            for (int g = 0; g < 4; ++g)
                tk[g] = __float2bfloat16(ak[mf][nf][g] + ba[g]);
            *reinterpret_cast<uint2*>(&ko[((size_t)s * HW + tok) * CDIM + cb]) =
                *reinterpret_cast<uint2*>(tk);
        }
    }
    #pragma unroll
    for (int nf = 0; nf < 2; ++nf) {
        const int c = cw0 + nf * 16 + lo16;
        const float bvv = bv[c];
        #pragma unroll
        for (int mf = 0; mf < 4; ++mf) {
            const int tb = t0 + mf * 16 + 4 * hi4;
            bf16 tv[4];
            #pragma unroll
            for (int g = 0; g < 4; ++g)
                tv[g] = __float2bfloat16(av[mf][nf][g] + bvv);
            *reinterpret_cast<uint2*>(&vt[((size_t)s * CDIM + c) * HW + tb]) =
                *reinterpret_cast<uint2*>(tv);
        }
    }
}

// ---------------------------------------------------------------------------
// Kernel 2: MFMA flash attention — round-16 double-buffered structure with
// ASYNC global_load_lds staging (no VGPR round-trip, no ds_writes for K/V).
// K: linear LDS dest + pre-swizzled global source (same XOR involution as
//    the read side; rule "both-sides-or-neither").
// V: token-chunk-major layout off = u*4096B + c*16B — lane-contiguous for
//    the DMA and bank-minimal on the PV read (no XOR needed).
// ---------------------------------------------------------------------------
__global__ __launch_bounds__(256)
void flash_mfma_kernel(const bf16* __restrict__ q, const bf16* __restrict__ k,
                       const bf16* __restrict__ vt, const float* __restrict__ img,
                       float* __restrict__ out)
{
    const int bid = blockIdx.x;
    const int s   = (bid & 7) * 4 + ((bid >> 3) & 3);
    const int t0  = (bid >> 5) * 64;

    const int tid  = threadIdx.x;
    const int wave = tid >> 6;
    const int lane = tid & 63;
    const int lo16 = lane & 15;
    const int hi4  = lane >> 4;

    extern __shared__ short SM[];
    // K buffers at 0 / 8192, V buffers at 16384 / 24576, Ps at 32768

    short8v qf[8];
    {
        const bf16* qp = q + ((size_t)s * HW + t0 + wave * 16 + lo16) * CDIM + hi4 * 8;
        #pragma unroll
        for (int kf = 0; kf < 8; ++kf)
            qf[kf] = *reinterpret_cast<const short8v*>(qp + kf * 32);
    }

    f32x4 Oacc[16];
    #pragma unroll
    for (int cf = 0; cf < 16; ++cf) Oacc[cf] = (f32x4){0.f, 0.f, 0.f, 0.f};
    float lp[4] = {0.f, 0.f, 0.f, 0.f};

    const bf16* kS  = k  + (size_t)s * HW * CDIM;
    const bf16* vtS = vt + (size_t)s * CDIM * HW;

    // async staging of KV tile kt_ into buffer buf (8 x 16B DMA per thread)
    auto stage = [&](int kt_, int buf) {
        short* Kb = SM + buf * 8192;
        short* Vb = SM + 16384 + buf * 8192;
        #pragma unroll
        for (int u = 0; u < 4; ++u) {
            // instr i covers rows 2i..2i+1; lane: row = 2i+(l>>5), chunk = l&31
            const int i   = wave * 4 + u;
            const int row = 2 * i + (lane >> 5);
            const int ch  = (lane & 31) ^ (row & 7);   // pre-swizzled source
            gl_lds16(kS + (size_t)(kt_ * KVT + row) * CDIM + ch * 8,
                     Kb + i * 512);
        }
        #pragma unroll
        for (int u = 0; u < 4; ++u) {
            // V: off(c,u) = u*2048 + c*8 shorts; lane c = wave*64 + l
            const int c = wave * 64 + lane;
            gl_lds16(vtS + (size_t)c * HW + kt_ * KVT + u * 8,
                     Vb + u * 2048 + wave * 512);
        }
    };

    // prologue: stage tile 0 into buffer 0
    stage(0, 0);
    __syncthreads();   // vmcnt drained by barrier semantics

    const int pvRow = lo16 * 32 + (hi4 ^ ((lo16 >> 1) & 3)) * 8;
    for (int kt = 0; kt < NKT; ++kt) {
        const int cur = kt & 1;
        short* Kc = SM + cur * 8192;
        short* Vc = SM + 16384 + cur * 8192;

        // async-stage tile kt+1 into the idle buffer (its readers finished
        // before the barrier that ended iteration kt-1)
        if (kt + 1 < NKT) stage(kt + 1, cur ^ 1);

        // ---- QK^T on current buffer ----
        f32x4 sa[2];
        sa[0] = (f32x4){0.f, 0.f, 0.f, 0.f};
        sa[1] = (f32x4){0.f, 0.f, 0.f, 0.f};
        __builtin_amdgcn_s_setprio(1);
        #pragma unroll
        for (int ks = 0; ks < 8; ++ks) {
            #pragma unroll
            for (int cf = 0; cf < 2; ++cf) {
                const int row = cf * 16 + lo16;
                short8v bfr = *reinterpret_cast<const short8v*>(
                    &Kc[row * 256 + ((4 * ks + hi4) ^ (lo16 & 7)) * 8]);
                sa[cf] = __builtin_amdgcn_mfma_f32_16x16x32_bf16(qf[ks], bfr, sa[cf], 0, 0, 0);
            }
        }
        __builtin_amdgcn_s_setprio(0);

        // ---- P = exp(S); lane-local l partials; P -> LDS swizzled ----
        #pragma unroll
        for (int cf = 0; cf < 2; ++cf)
            #pragma unroll
            for (int g = 0; g < 4; ++g) {
                const float e = __expf(sa[cf][g]);
                lp[g] += e;
                bf16 hb = __float2bfloat16(e);
                const int r = 4 * hi4 + g;
                const int ch = (2 * cf + (lo16 >> 3)) ^ ((r >> 1) & 3);
                SM[32768 + wave * 512 + r * 32 + ch * 8 + (lo16 & 7)] = *reinterpret_cast<short*>(&hb);
            }

        const short8v pa = *reinterpret_cast<const short8v*>(&SM[32768 + wave * 512 + pvRow]);

        // ---- PV on current buffer (token-chunk-major V layout) ----
        __builtin_amdgcn_s_setprio(1);
        #pragma unroll
        for (int cf = 0; cf < 16; ++cf) {
            const short8v vb = *reinterpret_cast<const short8v*>(
                &Vc[hi4 * 2048 + (cf * 16 + lo16) * 8]);
            Oacc[cf] = __builtin_amdgcn_mfma_f32_16x16x32_bf16(pa, vb, Oacc[cf], 0, 0, 0);
        }
        __builtin_amdgcn_s_setprio(0);

        __syncthreads();   // single barrier per tile; drains async DMA
    }

    // ---- epilogue ----
    float inv[4];
    #pragma unroll
    for (int g = 0; g < 4; ++g) {
        float l = lp[g];
        #pragma unroll
        for (int off = 1; off < 16; off <<= 1) l += __shfl_xor(l, off);
        inv[g] = 1.0f / l;
    }
    const float* imgS = img + (size_t)s * CDIM * HW;
    float*       outS = out + (size_t)s * CDIM * HW;
    const int tt = t0 + wave * 16 + 4 * hi4;
    #pragma unroll
    for (int cf = 0; cf < 16; ++cf) {
        const int c = cf * 16 + lo16;
        const float4 r4 = *reinterpret_cast<const float4*>(imgS + (size_t)c * HW + tt);
        float4 o;
        o.x = Oacc[cf][0] * inv[0] + r4.x;
        o.y = Oacc[cf][1] * inv[1] + r4.y;
        o.z = Oacc[cf][2] * inv[2] + r4.z;
        o.w = Oacc[cf][3] * inv[3] + r4.w;
        *reinterpret_cast<float4*>(outS + (size_t)c * HW + tt) = o;
    }
}

// ---------------------------------------------------------------------------
extern "C" void kernel_launch(void* const* d_in, const int* in_sizes, int n_in,
                              void* d_out, int out_size, void* d_ws, size_t ws_size,
                              hipStream_t stream)
{
    const float* img = (const float*)d_in[0];
    const float* dep = (const float*)d_in[1];
    const float* Wq  = (const float*)d_in[2];
    const float* bq  = (const float*)d_in[3];
    const float* Wk  = (const float*)d_in[4];
    const float* bk  = (const float*)d_in[5];
    const float* Wv  = (const float*)d_in[6];
    const float* bv  = (const float*)d_in[7];
    float* out = (float*)d_out;

    const size_t npt  = (size_t)NSLICE * HW * CDIM;
    const size_t need = 3 * npt * sizeof(bf16) + 3 * 65536 * sizeof(bf16);
    if (ws_size < need) {
        hipMemsetAsync(d_out, 0, (size_t)out_size * sizeof(float), stream);
        return;
    }

    bf16* q  = (bf16*)d_ws;        // token-major, prescaled
    bf16* k  = q + npt;            // token-major
    bf16* vt = k + npt;            // channel-major
    bf16* wt = vt + npt;           // [3][256][256] W^T

    hipFuncSetAttribute((const void*)flash_mfma_kernel,
                        hipFuncAttributeMaxDynamicSharedMemorySize,
                        FLASH_LDS_BYTES);

    wt_prep_kernel<<<dim3(3 * 256), 256, 0, stream>>>(Wq, Wk, Wv, wt);

    proj_q_kernel<<<dim3(NSLICE * 32), 256, 0, stream>>>(img, wt, bq, q);
    proj_kv_kernel<<<dim3(NSLICE * 32), 256, 0, stream>>>(dep, wt, bk, bv, k, vt);

    flash_mfma_kernel<<<dim3(NSLICE * 16), 256, FLASH_LDS_BYTES, stream>>>(
        q, k, vt, img, out);
}